// Round 1
// baseline (2323.065 us; speedup 1.0000x reference)
//
#include <hip/hip_runtime.h>
#include <hip/hip_bf16.h>
#include <math.h>

// ---------------------------------------------------------------------------
// AttentionEncoderModel on MI355X — fp32 correctness-first implementation.
// B=2 S=512 H=96 W=120, convs 3->16->16->16 (4x4 s2 p1, relu),
// flatten 2880 -> D=256, +pos, 4 transformer blocks (NH=8, DH=32, causal),
// final D->D, global standardization (ddof=1).
// ---------------------------------------------------------------------------

#define NIMG   1024      // B*S
#define CHUNK  256       // conv chunk images
#define NCHUNK 4
#define DMODEL 256
#define SEQ    512
#define NHEAD  8
#define DHEAD  32

// ---------------- conv1: 3->16, in 96x120 -> out 48x60 ----------------------
__global__ __launch_bounds__(256) void conv1_kernel(
    const float* __restrict__ in, const float* __restrict__ w,
    const float* __restrict__ bias, float* __restrict__ out, int n0) {
  __shared__ float wsm[768];  // 16*3*4*4
  int t = threadIdx.x;
  for (int i = t; i < 768; i += 256) wsm[i] = w[i];
  __syncthreads();
  int idx = blockIdx.x * 256 + t;          // over CHUNK*48*60 = 737280
  if (idx >= CHUNK * 48 * 60) return;
  int ox = idx % 60;
  int oy = (idx / 60) % 48;
  int nl = idx / (60 * 48);
  int n  = n0 + nl;
  int iy0 = oy * 2 - 1, ix0 = ox * 2 - 1;
  float win[3][16];
  #pragma unroll
  for (int ic = 0; ic < 3; ic++) {
    #pragma unroll
    for (int ky = 0; ky < 4; ky++) {
      int iy = iy0 + ky;
      #pragma unroll
      for (int kx = 0; kx < 4; kx++) {
        int ix = ix0 + kx;
        bool ok = (iy >= 0) && (iy < 96) && (ix >= 0) && (ix < 120);
        win[ic][ky * 4 + kx] = ok ? in[((n * 3 + ic) * 96 + iy) * 120 + ix] : 0.f;
      }
    }
  }
  #pragma unroll
  for (int oc = 0; oc < 16; oc++) {
    float acc = bias[oc];
    const float* wp = &wsm[oc * 48];
    #pragma unroll
    for (int ic = 0; ic < 3; ic++)
      #pragma unroll
      for (int k = 0; k < 16; k++)
        acc = fmaf(win[ic][k], wp[ic * 16 + k], acc);
    out[((nl * 16 + oc) * 48 + oy) * 60 + ox] = fmaxf(acc, 0.f);
  }
}

// ---------------- conv 16->16 (used for conv2 and conv3) --------------------
template <int IH, int IW, int OH, int OW>
__global__ __launch_bounds__(256) void conv16_kernel(
    const float* __restrict__ in, const float* __restrict__ w,
    const float* __restrict__ bias, float* __restrict__ out) {
  __shared__ float wsm[4096];  // 16*16*4*4
  int t = threadIdx.x;
  for (int i = t; i < 4096; i += 256) wsm[i] = w[i];
  __syncthreads();
  int idx = blockIdx.x * 256 + t;          // over CHUNK*OH*OW
  if (idx >= CHUNK * OH * OW) return;
  int ox = idx % OW;
  int oy = (idx / OW) % OH;
  int n  = idx / (OW * OH);
  int iy0 = oy * 2 - 1, ix0 = ox * 2 - 1;
  float acc[16];
  #pragma unroll
  for (int oc = 0; oc < 16; oc++) acc[oc] = bias[oc];
  for (int ic = 0; ic < 16; ic++) {
    float win[16];
    #pragma unroll
    for (int ky = 0; ky < 4; ky++) {
      int iy = iy0 + ky;
      #pragma unroll
      for (int kx = 0; kx < 4; kx++) {
        int ix = ix0 + kx;
        bool ok = (iy >= 0) && (iy < IH) && (ix >= 0) && (ix < IW);
        win[ky * 4 + kx] = ok ? in[((n * 16 + ic) * IH + iy) * IW + ix] : 0.f;
      }
    }
    #pragma unroll
    for (int oc = 0; oc < 16; oc++) {
      const float* wp = &wsm[(oc * 16 + ic) * 16];
      float a = acc[oc];
      #pragma unroll
      for (int k = 0; k < 16; k++) a = fmaf(win[k], wp[k], a);
      acc[oc] = a;
    }
  }
  #pragma unroll
  for (int oc = 0; oc < 16; oc++)
    out[((n * 16 + oc) * OH + oy) * OW + ox] = fmaxf(acc[oc], 0.f);
}

// ---------------- generic tiled fp32 GEMM -----------------------------------
// C[M,N] = epi(A[M,K] @ B[K,N] + bias).  M%64==0, N%64==0, K%16==0.
// EPI: 0 = bias, 1 = bias + exact GELU, 2 = bias + res[m*N+n], 3 = bias + pos[(m&511)*N+n]
template <int EPI>
__global__ __launch_bounds__(256) void gemm_kernel(
    const float* __restrict__ A, const float* __restrict__ B,
    const float* __restrict__ bias, const float* __restrict__ res,
    float* __restrict__ C, int M, int N, int K) {
  __shared__ float As[16][65];
  __shared__ float Bs[16][64];
  int t  = threadIdx.x;
  int m0 = blockIdx.y * 64, n0 = blockIdx.x * 64;
  int tx = t & 15, ty = t >> 4;
  int arow = t >> 4, acol = t & 15;   // A tile: 64 rows x 16 k
  int brow = t >> 6, bcol = t & 63;   // B tile: 16 k x 64 cols
  float acc[4][4] = {};
  for (int k0 = 0; k0 < K; k0 += 16) {
    #pragma unroll
    for (int i = 0; i < 4; i++) {
      int r = arow + i * 16;
      As[acol][r] = A[(m0 + r) * K + k0 + acol];
    }
    #pragma unroll
    for (int i = 0; i < 4; i++) {
      int r = brow + i * 4;
      Bs[r][bcol] = B[(k0 + r) * N + n0 + bcol];
    }
    __syncthreads();
    #pragma unroll
    for (int kk = 0; kk < 16; kk++) {
      float a[4], b[4];
      #pragma unroll
      for (int i = 0; i < 4; i++) a[i] = As[kk][ty + 16 * i];
      #pragma unroll
      for (int j = 0; j < 4; j++) b[j] = Bs[kk][tx + 16 * j];
      #pragma unroll
      for (int i = 0; i < 4; i++)
        #pragma unroll
        for (int j = 0; j < 4; j++)
          acc[i][j] = fmaf(a[i], b[j], acc[i][j]);
    }
    __syncthreads();
  }
  #pragma unroll
  for (int i = 0; i < 4; i++) {
    int m = m0 + ty + 16 * i;
    #pragma unroll
    for (int j = 0; j < 4; j++) {
      int n = n0 + tx + 16 * j;
      float v = acc[i][j] + bias[n];
      if (EPI == 1) v = 0.5f * v * (1.f + erff(v * 0.70710678118654752f));
      else if (EPI == 2) v += res[m * N + n];
      else if (EPI == 3) v += res[(m & (SEQ - 1)) * N + n];
      C[m * N + n] = v;
    }
  }
}

// ---------------- LayerNorm: one wave per row of 256 ------------------------
__global__ __launch_bounds__(256) void ln_kernel(
    const float* __restrict__ x, const float* __restrict__ g,
    const float* __restrict__ b, float* __restrict__ out) {
  int lane = threadIdx.x & 63;
  int wid  = threadIdx.x >> 6;
  int row  = blockIdx.x * 4 + wid;
  const float* xr = x + row * DMODEL;
  float v[4];
  #pragma unroll
  for (int i = 0; i < 4; i++) v[i] = xr[lane + 64 * i];
  float s = v[0] + v[1] + v[2] + v[3];
  #pragma unroll
  for (int o = 32; o >= 1; o >>= 1) s += __shfl_xor(s, o);
  float mu = s * (1.f / 256.f);
  float sq = 0.f;
  #pragma unroll
  for (int i = 0; i < 4; i++) { float d = v[i] - mu; sq = fmaf(d, d, sq); }
  #pragma unroll
  for (int o = 32; o >= 1; o >>= 1) sq += __shfl_xor(sq, o);
  float rs = rsqrtf(sq * (1.f / 256.f) + 1e-5f);
  float* orow = out + row * DMODEL;
  #pragma unroll
  for (int i = 0; i < 4; i++) {
    int c = lane + 64 * i;
    orow[c] = (v[i] - mu) * rs * g[c] + b[c];
  }
}

// ---------------- QK^T + causal softmax: one wave per query row -------------
// c: [2, 512, 768] (q|k|v), P: [2, 8, 512, 512]
__global__ __launch_bounds__(256) void attn_qk_kernel(
    const float* __restrict__ c, float* __restrict__ P) {
  int lane = threadIdx.x & 63;
  int wid  = threadIdx.x >> 6;
  int gw = blockIdx.x * 4 + wid;          // 0 .. 8191
  int i = gw & (SEQ - 1);
  int h = (gw >> 9) & (NHEAD - 1);
  int b = gw >> 12;
  const float* qr = c + (b * SEQ + i) * 768 + h * DHEAD;
  float q[DHEAD];
  #pragma unroll
  for (int d = 0; d < DHEAD; d++) q[d] = qr[d];
  const float* kbase = c + b * SEQ * 768 + DMODEL + h * DHEAD;
  float lg[8];
  float mx = -1e30f;
  #pragma unroll
  for (int jj = 0; jj < 8; jj++) {
    int j = lane + jj * 64;
    float acc;
    if (j <= i) {
      const float* kr = kbase + j * 768;
      acc = 0.f;
      #pragma unroll
      for (int d = 0; d < DHEAD; d++) acc = fmaf(q[d], kr[d], acc);
      acc *= 0.17677669529663687f;        // 1/sqrt(32)
      mx = fmaxf(mx, acc);
    } else {
      acc = -1e30f;
    }
    lg[jj] = acc;
  }
  #pragma unroll
  for (int o = 32; o >= 1; o >>= 1) mx = fmaxf(mx, __shfl_xor(mx, o));
  float sum = 0.f;
  #pragma unroll
  for (int jj = 0; jj < 8; jj++) {
    float e = (lg[jj] > -1e29f) ? expf(lg[jj] - mx) : 0.f;
    lg[jj] = e;
    sum += e;
  }
  #pragma unroll
  for (int o = 32; o >= 1; o >>= 1) sum += __shfl_xor(sum, o);
  float inv = 1.f / sum;
  float* pr = P + (((size_t)(b * NHEAD + h) * SEQ) + i) * SEQ;
  #pragma unroll
  for (int jj = 0; jj < 8; jj++) pr[lane + jj * 64] = lg[jj] * inv;
}

// ---------------- P @ V with in-place residual add into x -------------------
__global__ __launch_bounds__(256) void attn_pv_kernel(
    const float* __restrict__ P, const float* __restrict__ c,
    float* __restrict__ x) {
  int idx = blockIdx.x * 256 + threadIdx.x;  // over 2*8*512*32 = 262144
  int d = idx & (DHEAD - 1);
  int i = (idx >> 5) & (SEQ - 1);
  int h = (idx >> 14) & (NHEAD - 1);
  int b = idx >> 17;
  const float* pr = P + (((size_t)(b * NHEAD + h) * SEQ) + i) * SEQ;
  const float* vbase = c + b * SEQ * 768 + 2 * DMODEL + h * DHEAD + d;
  float acc = 0.f;
  for (int j = 0; j <= i; j++)
    acc = fmaf(pr[j], vbase[j * 768], acc);
  x[(b * SEQ + i) * DMODEL + h * DHEAD + d] += acc;
}

// ---------------- global standardization ------------------------------------
__global__ __launch_bounds__(256) void reduce1_kernel(
    const float* __restrict__ enc, double* __restrict__ part) {
  int t = threadIdx.x;
  double s = 0.0, q = 0.0;
  for (int i = blockIdx.x * 256 + t; i < 262144; i += 256 * 256) {
    double v = (double)enc[i];
    s += v; q += v * v;
  }
  #pragma unroll
  for (int o = 32; o >= 1; o >>= 1) { s += __shfl_xor(s, o); q += __shfl_xor(q, o); }
  __shared__ double ls[4], lq[4];
  int lane = t & 63, wid = t >> 6;
  if (lane == 0) { ls[wid] = s; lq[wid] = q; }
  __syncthreads();
  if (t == 0) {
    double S = ls[0] + ls[1] + ls[2] + ls[3];
    double Q = lq[0] + lq[1] + lq[2] + lq[3];
    part[blockIdx.x * 2]     = S;
    part[blockIdx.x * 2 + 1] = Q;
  }
}

__global__ __launch_bounds__(256) void reduce2_kernel(
    const double* __restrict__ part, float* __restrict__ stats) {
  int t = threadIdx.x;
  double s = part[t * 2], q = part[t * 2 + 1];
  #pragma unroll
  for (int o = 32; o >= 1; o >>= 1) { s += __shfl_xor(s, o); q += __shfl_xor(q, o); }
  __shared__ double ls[4], lq[4];
  int lane = t & 63, wid = t >> 6;
  if (lane == 0) { ls[wid] = s; lq[wid] = q; }
  __syncthreads();
  if (t == 0) {
    double S = ls[0] + ls[1] + ls[2] + ls[3];
    double Q = lq[0] + lq[1] + lq[2] + lq[3];
    double n = 262144.0;
    double mean = S / n;
    double var  = (Q - n * mean * mean) / (n - 1.0);
    stats[0] = (float)mean;
    stats[1] = (float)(1.0 / sqrt(var));
  }
}

__global__ __launch_bounds__(256) void norm_kernel(
    const float* __restrict__ enc, const float* __restrict__ stats,
    float* __restrict__ out) {
  int i = blockIdx.x * 256 + threadIdx.x;
  float mean = stats[0], inv = stats[1];
  out[i] = (enc[i] - mean) * inv + 1e-10f;
}

// ---------------------------------------------------------------------------
extern "C" void kernel_launch(void* const* d_in, const int* in_sizes, int n_in,
                              void* d_out, int out_size, void* d_ws, size_t ws_size,
                              hipStream_t stream) {
  const float* state   = (const float*)d_in[0];
  const float* conv_w1 = (const float*)d_in[1];
  const float* conv_b1 = (const float*)d_in[2];
  const float* conv_w2 = (const float*)d_in[3];
  const float* conv_b2 = (const float*)d_in[4];
  const float* conv_w3 = (const float*)d_in[5];
  const float* conv_b3 = (const float*)d_in[6];
  const float* pre_w   = (const float*)d_in[7];
  const float* pre_b   = (const float*)d_in[8];
  const float* pos_w   = (const float*)d_in[9];
  const float* ln1_g   = (const float*)d_in[10];
  const float* ln1_b   = (const float*)d_in[11];
  const float* enc_w   = (const float*)d_in[12];
  const float* enc_bi  = (const float*)d_in[13];
  const float* ln2_g   = (const float*)d_in[14];
  const float* ln2_b   = (const float*)d_in[15];
  const float* ffn_w1  = (const float*)d_in[16];
  const float* ffn_b1  = (const float*)d_in[17];
  const float* ffn_w2  = (const float*)d_in[18];
  const float* ffn_b2  = (const float*)d_in[19];
  const float* emb_w   = (const float*)d_in[20];
  const float* emb_b   = (const float*)d_in[21];
  float* out = (float*)d_out;
  char* ws = (char*)d_ws;

  // ws layout (bytes)
  const size_t OFF_C1C = 0;                         // 256*16*48*60*4 = 47185920
  const size_t OFF_C2C = OFF_C1C + 47185920;        // 256*16*24*30*4 = 11796480
  const size_t OFF_C3  = OFF_C2C + 11796480;        // 1024*2880*4    = 11796480
  const size_t OFF_X   = OFF_C3  + 11796480;        // 1024*256*4     = 1048576
  const size_t OFF_XN  = OFF_X   + 1048576;         // 1048576
  const size_t OFF_QKV = OFF_XN  + 1048576;         // 1024*768*4     = 3145728
  const size_t OFF_P   = OFF_QKV + 3145728;         // 2*8*512*512*4  = 16777216
  const size_t OFF_H1  = OFF_P   + 16777216;        // 1024*1024*4    = 4194304
  const size_t OFF_ENC = OFF_H1  + 4194304;         // 1048576
  const size_t OFF_RED = OFF_ENC + 1048576;         // 256*2*8 + 8

  float*  c1c  = (float*)(ws + OFF_C1C);
  float*  c2c  = (float*)(ws + OFF_C2C);
  float*  c3   = (float*)(ws + OFF_C3);
  float*  x    = (float*)(ws + OFF_X);
  float*  xn   = (float*)(ws + OFF_XN);
  float*  qkv  = (float*)(ws + OFF_QKV);
  float*  P    = (float*)(ws + OFF_P);
  float*  h1   = (float*)(ws + OFF_H1);
  float*  encb = (float*)(ws + OFF_ENC);
  double* part = (double*)(ws + OFF_RED);
  float*  stats= (float*)(ws + OFF_RED + 4096);

  // conv pipeline, chunked over images to bound ws
  for (int chunk = 0; chunk < NCHUNK; chunk++) {
    conv1_kernel<<<2880, 256, 0, stream>>>(state, conv_w1, conv_b1, c1c, chunk * CHUNK);
    conv16_kernel<48, 60, 24, 30><<<720, 256, 0, stream>>>(c1c, conv_w2, conv_b2, c2c);
    conv16_kernel<24, 30, 12, 15><<<180, 256, 0, stream>>>(
        c2c, conv_w3, conv_b3, c3 + (size_t)chunk * CHUNK * 2880);
  }

  // pre projection + positional embedding: x = c3 @ pre_w + pre_b + pos
  gemm_kernel<3><<<dim3(4, 16), 256, 0, stream>>>(c3, pre_w, pre_b, pos_w, x,
                                                  1024, 256, 2880);

  for (int k = 0; k < 4; k++) {
    ln_kernel<<<256, 256, 0, stream>>>(x, ln1_g + k * 256, ln1_b + k * 256, xn);
    gemm_kernel<0><<<dim3(12, 16), 256, 0, stream>>>(
        xn, enc_w + (size_t)k * 256 * 768, enc_bi + k * 768, nullptr, qkv,
        1024, 768, 256);
    attn_qk_kernel<<<2048, 256, 0, stream>>>(qkv, P);
    attn_pv_kernel<<<1024, 256, 0, stream>>>(P, qkv, x);
    ln_kernel<<<256, 256, 0, stream>>>(x, ln2_g + k * 256, ln2_b + k * 256, x);
    gemm_kernel<1><<<dim3(16, 16), 256, 0, stream>>>(
        x, ffn_w1 + (size_t)k * 256 * 1024, ffn_b1 + k * 1024, nullptr, h1,
        1024, 1024, 256);
    gemm_kernel<2><<<dim3(4, 16), 256, 0, stream>>>(
        h1, ffn_w2 + (size_t)k * 1024 * 256, ffn_b2 + k * 256, x, x,
        1024, 256, 1024);
  }

  gemm_kernel<0><<<dim3(4, 16), 256, 0, stream>>>(x, emb_w, emb_b, nullptr, encb,
                                                  1024, 256, 256);
  reduce1_kernel<<<256, 256, 0, stream>>>(encb, part);
  reduce2_kernel<<<1, 256, 0, stream>>>(part, stats);
  norm_kernel<<<1024, 256, 0, stream>>>(encb, stats, out);
}

// Round 2
// 1948.508 us; speedup vs baseline: 1.1922x; 1.1922x over previous
//
#include <hip/hip_runtime.h>
#include <hip/hip_bf16.h>
#include <math.h>

// ---------------------------------------------------------------------------
// AttentionEncoderModel on MI355X — round 2: GEMM overhaul.
// Split-K atomic GEMMs (linear epilogues pre-initialized), double-buffered
// LDS, b128 fragment reads. Convs/attention unchanged this round.
// ---------------------------------------------------------------------------

#define NIMG   1024      // B*S
#define CHUNK  256       // conv chunk images
#define NCHUNK 4
#define DMODEL 256
#define SEQ    512
#define NHEAD  8
#define DHEAD  32

// ---------------- conv1: 3->16, in 96x120 -> out 48x60 ----------------------
__global__ __launch_bounds__(256) void conv1_kernel(
    const float* __restrict__ in, const float* __restrict__ w,
    const float* __restrict__ bias, float* __restrict__ out, int n0) {
  __shared__ float wsm[768];  // 16*3*4*4
  int t = threadIdx.x;
  for (int i = t; i < 768; i += 256) wsm[i] = w[i];
  __syncthreads();
  int idx = blockIdx.x * 256 + t;          // over CHUNK*48*60 = 737280
  if (idx >= CHUNK * 48 * 60) return;
  int ox = idx % 60;
  int oy = (idx / 60) % 48;
  int nl = idx / (60 * 48);
  int n  = n0 + nl;
  int iy0 = oy * 2 - 1, ix0 = ox * 2 - 1;
  float win[3][16];
  #pragma unroll
  for (int ic = 0; ic < 3; ic++) {
    #pragma unroll
    for (int ky = 0; ky < 4; ky++) {
      int iy = iy0 + ky;
      #pragma unroll
      for (int kx = 0; kx < 4; kx++) {
        int ix = ix0 + kx;
        bool ok = (iy >= 0) && (iy < 96) && (ix >= 0) && (ix < 120);
        win[ic][ky * 4 + kx] = ok ? in[((n * 3 + ic) * 96 + iy) * 120 + ix] : 0.f;
      }
    }
  }
  #pragma unroll
  for (int oc = 0; oc < 16; oc++) {
    float acc = bias[oc];
    const float* wp = &wsm[oc * 48];
    #pragma unroll
    for (int ic = 0; ic < 3; ic++)
      #pragma unroll
      for (int k = 0; k < 16; k++)
        acc = fmaf(win[ic][k], wp[ic * 16 + k], acc);
    out[((nl * 16 + oc) * 48 + oy) * 60 + ox] = fmaxf(acc, 0.f);
  }
}

// ---------------- conv 16->16 (used for conv2 and conv3) --------------------
template <int IH, int IW, int OH, int OW>
__global__ __launch_bounds__(256) void conv16_kernel(
    const float* __restrict__ in, const float* __restrict__ w,
    const float* __restrict__ bias, float* __restrict__ out) {
  __shared__ float wsm[4096];  // 16*16*4*4
  int t = threadIdx.x;
  for (int i = t; i < 4096; i += 256) wsm[i] = w[i];
  __syncthreads();
  int idx = blockIdx.x * 256 + t;          // over CHUNK*OH*OW
  if (idx >= CHUNK * OH * OW) return;
  int ox = idx % OW;
  int oy = (idx / OW) % OH;
  int n  = idx / (OW * OH);
  int iy0 = oy * 2 - 1, ix0 = ox * 2 - 1;
  float acc[16];
  #pragma unroll
  for (int oc = 0; oc < 16; oc++) acc[oc] = bias[oc];
  for (int ic = 0; ic < 16; ic++) {
    float win[16];
    #pragma unroll
    for (int ky = 0; ky < 4; ky++) {
      int iy = iy0 + ky;
      #pragma unroll
      for (int kx = 0; kx < 4; kx++) {
        int ix = ix0 + kx;
        bool ok = (iy >= 0) && (iy < IH) && (ix >= 0) && (ix < IW);
        win[ky * 4 + kx] = ok ? in[((n * 16 + ic) * IH + iy) * IW + ix] : 0.f;
      }
    }
    #pragma unroll
    for (int oc = 0; oc < 16; oc++) {
      const float* wp = &wsm[(oc * 16 + ic) * 16];
      float a = acc[oc];
      #pragma unroll
      for (int k = 0; k < 16; k++) a = fmaf(win[k], wp[k], a);
      acc[oc] = a;
    }
  }
  #pragma unroll
  for (int oc = 0; oc < 16; oc++)
    out[((n * 16 + oc) * OH + oy) * OW + ox] = fmaxf(acc[oc], 0.f);
}

// ---------------- tiled fp32 GEMM, double-buffered, optional split-K --------
// Tile 64x64, 256 threads, micro 4x4 (contiguous rows/cols -> b128 LDS reads).
// ATOMIC=true: C += A@B partial (grid.z = splits, klen = K per split),
//              C must be pre-initialized with bias (+pos/residual).
// ATOMIC=false: C = epi(A@B + bias); EPI: 0=bias, 1=bias+exact GELU,
//              2=bias+res.
template <int EPI, bool ATOMIC>
__global__ __launch_bounds__(256) void gemm2_kernel(
    const float* __restrict__ A, const float* __restrict__ B,
    const float* __restrict__ bias, const float* __restrict__ res,
    float* __restrict__ C, int M, int N, int K, int klen) {
  __shared__ float As[2][16][68];   // [buf][k][row], pad 68 keeps b128 align
  __shared__ float Bs[2][16][64];   // [buf][k][col]
  int t = threadIdx.x;
  int m0 = blockIdx.y * 64, n0 = blockIdx.x * 64;
  int kb = blockIdx.z * klen;
  int arow = t >> 4, acol = t & 15;  // A tile loader: 64 rows x 16 k
  int brow = t >> 6, bcol = t & 63;  // B tile loader: 16 k x 64 cols
  int tx = t & 15, ty = t >> 4;      // micro tile: rows ty*4.., cols tx*4..
  float ra[4], rb[4];
  float acc[4][4] = {};

  #pragma unroll
  for (int i = 0; i < 4; i++) ra[i] = A[(m0 + arow + 16 * i) * K + kb + acol];
  #pragma unroll
  for (int i = 0; i < 4; i++) rb[i] = B[(kb + brow + 4 * i) * N + n0 + bcol];
  #pragma unroll
  for (int i = 0; i < 4; i++) As[0][acol][arow + 16 * i] = ra[i];
  #pragma unroll
  for (int i = 0; i < 4; i++) Bs[0][brow + 4 * i][bcol] = rb[i];
  __syncthreads();

  int nk = klen >> 4;
  for (int it = 0; it < nk; ++it) {
    int buf = it & 1;
    if (it + 1 < nk) {
      int k0 = kb + 16 * (it + 1);
      #pragma unroll
      for (int i = 0; i < 4; i++) ra[i] = A[(m0 + arow + 16 * i) * K + k0 + acol];
      #pragma unroll
      for (int i = 0; i < 4; i++) rb[i] = B[(k0 + brow + 4 * i) * N + n0 + bcol];
    }
    #pragma unroll
    for (int kk = 0; kk < 16; kk++) {
      float a[4], b[4];
      #pragma unroll
      for (int i = 0; i < 4; i++) a[i] = As[buf][kk][ty * 4 + i];
      #pragma unroll
      for (int j = 0; j < 4; j++) b[j] = Bs[buf][kk][tx * 4 + j];
      #pragma unroll
      for (int i = 0; i < 4; i++)
        #pragma unroll
        for (int j = 0; j < 4; j++)
          acc[i][j] = fmaf(a[i], b[j], acc[i][j]);
    }
    if (it + 1 < nk) {
      #pragma unroll
      for (int i = 0; i < 4; i++) As[buf ^ 1][acol][arow + 16 * i] = ra[i];
      #pragma unroll
      for (int i = 0; i < 4; i++) Bs[buf ^ 1][brow + 4 * i][bcol] = rb[i];
    }
    __syncthreads();
  }

  #pragma unroll
  for (int i = 0; i < 4; i++) {
    int m = m0 + ty * 4 + i;
    if (ATOMIC) {
      #pragma unroll
      for (int j = 0; j < 4; j++)
        atomicAdd(&C[m * N + n0 + tx * 4 + j], acc[i][j]);
    } else {
      #pragma unroll
      for (int j = 0; j < 4; j++) {
        int n = n0 + tx * 4 + j;
        float v = acc[i][j] + bias[n];
        if (EPI == 1) v = 0.5f * v * (1.f + erff(v * 0.70710678118654752f));
        else if (EPI == 2) v += res[m * N + n];
        C[m * N + n] = v;
      }
    }
  }
}

// ---------------- small init / bias kernels ---------------------------------
__global__ __launch_bounds__(256) void initc_pre_kernel(
    float* __restrict__ C, const float* __restrict__ bias,
    const float* __restrict__ pos) {
  int idx = blockIdx.x * 256 + threadIdx.x;   // 1024*256
  int n = idx & 255;
  int m = idx >> 8;
  C[idx] = bias[n] + pos[(m & (SEQ - 1)) * 256 + n];
}

__global__ __launch_bounds__(256) void initc_bias_kernel(
    float* __restrict__ C, const float* __restrict__ bias, int N) {
  int idx = blockIdx.x * 256 + threadIdx.x;
  C[idx] = bias[idx % N];
}

__global__ __launch_bounds__(256) void addbias_kernel(
    float* __restrict__ C, const float* __restrict__ bias) {
  int idx = blockIdx.x * 256 + threadIdx.x;   // N=256 only
  C[idx] += bias[idx & 255];
}

// ---------------- LayerNorm: one wave per row of 256 ------------------------
__global__ __launch_bounds__(256) void ln_kernel(
    const float* __restrict__ x, const float* __restrict__ g,
    const float* __restrict__ b, float* __restrict__ out) {
  int lane = threadIdx.x & 63;
  int wid  = threadIdx.x >> 6;
  int row  = blockIdx.x * 4 + wid;
  const float* xr = x + row * DMODEL;
  float v[4];
  #pragma unroll
  for (int i = 0; i < 4; i++) v[i] = xr[lane + 64 * i];
  float s = v[0] + v[1] + v[2] + v[3];
  #pragma unroll
  for (int o = 32; o >= 1; o >>= 1) s += __shfl_xor(s, o);
  float mu = s * (1.f / 256.f);
  float sq = 0.f;
  #pragma unroll
  for (int i = 0; i < 4; i++) { float d = v[i] - mu; sq = fmaf(d, d, sq); }
  #pragma unroll
  for (int o = 32; o >= 1; o >>= 1) sq += __shfl_xor(sq, o);
  float rs = rsqrtf(sq * (1.f / 256.f) + 1e-5f);
  float* orow = out + row * DMODEL;
  #pragma unroll
  for (int i = 0; i < 4; i++) {
    int c = lane + 64 * i;
    orow[c] = (v[i] - mu) * rs * g[c] + b[c];
  }
}

// ---------------- QK^T + causal softmax: one wave per query row -------------
__global__ __launch_bounds__(256) void attn_qk_kernel(
    const float* __restrict__ c, float* __restrict__ P) {
  int lane = threadIdx.x & 63;
  int wid  = threadIdx.x >> 6;
  int gw = blockIdx.x * 4 + wid;          // 0 .. 8191
  int i = gw & (SEQ - 1);
  int h = (gw >> 9) & (NHEAD - 1);
  int b = gw >> 12;
  const float* qr = c + (b * SEQ + i) * 768 + h * DHEAD;
  float q[DHEAD];
  #pragma unroll
  for (int d = 0; d < DHEAD; d++) q[d] = qr[d];
  const float* kbase = c + b * SEQ * 768 + DMODEL + h * DHEAD;
  float lg[8];
  float mx = -1e30f;
  #pragma unroll
  for (int jj = 0; jj < 8; jj++) {
    int j = lane + jj * 64;
    float acc;
    if (j <= i) {
      const float* kr = kbase + j * 768;
      acc = 0.f;
      #pragma unroll
      for (int d = 0; d < DHEAD; d++) acc = fmaf(q[d], kr[d], acc);
      acc *= 0.17677669529663687f;        // 1/sqrt(32)
      mx = fmaxf(mx, acc);
    } else {
      acc = -1e30f;
    }
    lg[jj] = acc;
  }
  #pragma unroll
  for (int o = 32; o >= 1; o >>= 1) mx = fmaxf(mx, __shfl_xor(mx, o));
  float sum = 0.f;
  #pragma unroll
  for (int jj = 0; jj < 8; jj++) {
    float e = (lg[jj] > -1e29f) ? expf(lg[jj] - mx) : 0.f;
    lg[jj] = e;
    sum += e;
  }
  #pragma unroll
  for (int o = 32; o >= 1; o >>= 1) sum += __shfl_xor(sum, o);
  float inv = 1.f / sum;
  float* pr = P + (((size_t)(b * NHEAD + h) * SEQ) + i) * SEQ;
  #pragma unroll
  for (int jj = 0; jj < 8; jj++) pr[lane + jj * 64] = lg[jj] * inv;
}

// ---------------- P @ V with in-place residual add into x -------------------
__global__ __launch_bounds__(256) void attn_pv_kernel(
    const float* __restrict__ P, const float* __restrict__ c,
    float* __restrict__ x) {
  int idx = blockIdx.x * 256 + threadIdx.x;  // over 2*8*512*32 = 262144
  int d = idx & (DHEAD - 1);
  int i = (idx >> 5) & (SEQ - 1);
  int h = (idx >> 14) & (NHEAD - 1);
  int b = idx >> 17;
  const float* pr = P + (((size_t)(b * NHEAD + h) * SEQ) + i) * SEQ;
  const float* vbase = c + b * SEQ * 768 + 2 * DMODEL + h * DHEAD + d;
  float acc = 0.f;
  for (int j = 0; j <= i; j++)
    acc = fmaf(pr[j], vbase[j * 768], acc);
  x[(b * SEQ + i) * DMODEL + h * DHEAD + d] += acc;
}

// ---------------- global standardization ------------------------------------
__global__ __launch_bounds__(256) void reduce1_kernel(
    const float* __restrict__ enc, double* __restrict__ part) {
  int t = threadIdx.x;
  double s = 0.0, q = 0.0;
  for (int i = blockIdx.x * 256 + t; i < 262144; i += 256 * 256) {
    double v = (double)enc[i];
    s += v; q += v * v;
  }
  #pragma unroll
  for (int o = 32; o >= 1; o >>= 1) { s += __shfl_xor(s, o); q += __shfl_xor(q, o); }
  __shared__ double ls[4], lq[4];
  int lane = t & 63, wid = t >> 6;
  if (lane == 0) { ls[wid] = s; lq[wid] = q; }
  __syncthreads();
  if (t == 0) {
    part[blockIdx.x * 2]     = ls[0] + ls[1] + ls[2] + ls[3];
    part[blockIdx.x * 2 + 1] = lq[0] + lq[1] + lq[2] + lq[3];
  }
}

__global__ __launch_bounds__(256) void reduce2_kernel(
    const double* __restrict__ part, float* __restrict__ stats) {
  int t = threadIdx.x;
  double s = part[t * 2], q = part[t * 2 + 1];
  #pragma unroll
  for (int o = 32; o >= 1; o >>= 1) { s += __shfl_xor(s, o); q += __shfl_xor(q, o); }
  __shared__ double ls[4], lq[4];
  int lane = t & 63, wid = t >> 6;
  if (lane == 0) { ls[wid] = s; lq[wid] = q; }
  __syncthreads();
  if (t == 0) {
    double S = ls[0] + ls[1] + ls[2] + ls[3];
    double Q = lq[0] + lq[1] + lq[2] + lq[3];
    double n = 262144.0;
    double mean = S / n;
    double var  = (Q - n * mean * mean) / (n - 1.0);
    stats[0] = (float)mean;
    stats[1] = (float)(1.0 / sqrt(var));
  }
}

__global__ __launch_bounds__(256) void norm_kernel(
    const float* __restrict__ enc, const float* __restrict__ stats,
    float* __restrict__ out) {
  int i = blockIdx.x * 256 + threadIdx.x;
  float mean = stats[0], inv = stats[1];
  out[i] = (enc[i] - mean) * inv + 1e-10f;
}

// ---------------------------------------------------------------------------
extern "C" void kernel_launch(void* const* d_in, const int* in_sizes, int n_in,
                              void* d_out, int out_size, void* d_ws, size_t ws_size,
                              hipStream_t stream) {
  const float* state   = (const float*)d_in[0];
  const float* conv_w1 = (const float*)d_in[1];
  const float* conv_b1 = (const float*)d_in[2];
  const float* conv_w2 = (const float*)d_in[3];
  const float* conv_b2 = (const float*)d_in[4];
  const float* conv_w3 = (const float*)d_in[5];
  const float* conv_b3 = (const float*)d_in[6];
  const float* pre_w   = (const float*)d_in[7];
  const float* pre_b   = (const float*)d_in[8];
  const float* pos_w   = (const float*)d_in[9];
  const float* ln1_g   = (const float*)d_in[10];
  const float* ln1_b   = (const float*)d_in[11];
  const float* enc_w   = (const float*)d_in[12];
  const float* enc_bi  = (const float*)d_in[13];
  const float* ln2_g   = (const float*)d_in[14];
  const float* ln2_b   = (const float*)d_in[15];
  const float* ffn_w1  = (const float*)d_in[16];
  const float* ffn_b1  = (const float*)d_in[17];
  const float* ffn_w2  = (const float*)d_in[18];
  const float* ffn_b2  = (const float*)d_in[19];
  const float* emb_w   = (const float*)d_in[20];
  const float* emb_b   = (const float*)d_in[21];
  float* out = (float*)d_out;
  char* ws = (char*)d_ws;

  const size_t OFF_C1C = 0;                         // 47185920
  const size_t OFF_C2C = OFF_C1C + 47185920;        // 11796480
  const size_t OFF_C3  = OFF_C2C + 11796480;        // 11796480
  const size_t OFF_X   = OFF_C3  + 11796480;        // 1048576
  const size_t OFF_XN  = OFF_X   + 1048576;         // 1048576
  const size_t OFF_QKV = OFF_XN  + 1048576;         // 3145728
  const size_t OFF_P   = OFF_QKV + 3145728;         // 16777216
  const size_t OFF_H1  = OFF_P   + 16777216;        // 4194304
  const size_t OFF_ENC = OFF_H1  + 4194304;         // 1048576
  const size_t OFF_RED = OFF_ENC + 1048576;

  float*  c1c  = (float*)(ws + OFF_C1C);
  float*  c2c  = (float*)(ws + OFF_C2C);
  float*  c3   = (float*)(ws + OFF_C3);
  float*  x    = (float*)(ws + OFF_X);
  float*  xn   = (float*)(ws + OFF_XN);
  float*  qkv  = (float*)(ws + OFF_QKV);
  float*  P    = (float*)(ws + OFF_P);
  float*  h1   = (float*)(ws + OFF_H1);
  float*  encb = (float*)(ws + OFF_ENC);
  double* part = (double*)(ws + OFF_RED);
  float*  stats= (float*)(ws + OFF_RED + 4096);

  for (int chunk = 0; chunk < NCHUNK; chunk++) {
    conv1_kernel<<<2880, 256, 0, stream>>>(state, conv_w1, conv_b1, c1c, chunk * CHUNK);
    conv16_kernel<48, 60, 24, 30><<<720, 256, 0, stream>>>(c1c, conv_w2, conv_b2, c2c);
    conv16_kernel<24, 30, 12, 15><<<180, 256, 0, stream>>>(
        c2c, conv_w3, conv_b3, c3 + (size_t)chunk * CHUNK * 2880);
  }

  // pre projection: x = bias + pos, then split-K atomic accumulate (S=12)
  initc_pre_kernel<<<1024, 256, 0, stream>>>(x, pre_b, pos_w);
  gemm2_kernel<0, true><<<dim3(4, 16, 12), 256, 0, stream>>>(
      c3, pre_w, nullptr, nullptr, x, 1024, 256, 2880, 240);

  for (int k = 0; k < 4; k++) {
    ln_kernel<<<256, 256, 0, stream>>>(x, ln1_g + k * 256, ln1_b + k * 256, xn);
    // qkv: init bias, split-K S=2
    initc_bias_kernel<<<3072, 256, 0, stream>>>(qkv, enc_bi + k * 768, 768);
    gemm2_kernel<0, true><<<dim3(12, 16, 2), 256, 0, stream>>>(
        xn, enc_w + (size_t)k * 256 * 768, nullptr, nullptr, qkv,
        1024, 768, 256, 128);
    attn_qk_kernel<<<2048, 256, 0, stream>>>(qkv, P);
    attn_pv_kernel<<<1024, 256, 0, stream>>>(P, qkv, x);
    ln_kernel<<<256, 256, 0, stream>>>(x, ln2_g + k * 256, ln2_b + k * 256, x);
    // ffn1: direct with GELU epilogue (grid already 256 blocks)
    gemm2_kernel<1, false><<<dim3(16, 16, 1), 256, 0, stream>>>(
        x, ffn_w1 + (size_t)k * 256 * 1024, ffn_b1 + k * 1024, nullptr, h1,
        1024, 1024, 256, 256);
    // ffn2: x += b2, then split-K S=8 atomic accumulate into x
    addbias_kernel<<<1024, 256, 0, stream>>>(x, ffn_b2 + k * 256);
    gemm2_kernel<0, true><<<dim3(4, 16, 8), 256, 0, stream>>>(
        h1, ffn_w2 + (size_t)k * 1024 * 256, nullptr, nullptr, x,
        1024, 256, 1024, 128);
  }

  // final projection: encb = emb_b, split-K S=4
  initc_bias_kernel<<<1024, 256, 0, stream>>>(encb, emb_b, 256);
  gemm2_kernel<0, true><<<dim3(4, 16, 4), 256, 0, stream>>>(
      x, emb_w, nullptr, nullptr, encb, 1024, 256, 256, 64);

  reduce1_kernel<<<256, 256, 0, stream>>>(encb, part);
  reduce2_kernel<<<1, 256, 0, stream>>>(part, stats);
  norm_kernel<<<1024, 256, 0, stream>>>(encb, stats, out);
}

// Round 3
// 1347.652 us; speedup vs baseline: 1.7238x; 1.4459x over previous
//
#include <hip/hip_runtime.h>
#include <hip/hip_bf16.h>
#include <math.h>

// ---------------------------------------------------------------------------
// AttentionEncoderModel on MI355X — round 3: fused flash attention.
// Split-K atomic GEMMs kept from round 2. Convs unchanged.
// ---------------------------------------------------------------------------

#define NIMG   1024      // B*S
#define CHUNK  256       // conv chunk images
#define NCHUNK 4
#define DMODEL 256
#define SEQ    512
#define NHEAD  8
#define DHEAD  32

// ---------------- conv1: 3->16, in 96x120 -> out 48x60 ----------------------
__global__ __launch_bounds__(256) void conv1_kernel(
    const float* __restrict__ in, const float* __restrict__ w,
    const float* __restrict__ bias, float* __restrict__ out, int n0) {
  __shared__ float wsm[768];  // 16*3*4*4
  int t = threadIdx.x;
  for (int i = t; i < 768; i += 256) wsm[i] = w[i];
  __syncthreads();
  int idx = blockIdx.x * 256 + t;          // over CHUNK*48*60 = 737280
  if (idx >= CHUNK * 48 * 60) return;
  int ox = idx % 60;
  int oy = (idx / 60) % 48;
  int nl = idx / (60 * 48);
  int n  = n0 + nl;
  int iy0 = oy * 2 - 1, ix0 = ox * 2 - 1;
  float win[3][16];
  #pragma unroll
  for (int ic = 0; ic < 3; ic++) {
    #pragma unroll
    for (int ky = 0; ky < 4; ky++) {
      int iy = iy0 + ky;
      #pragma unroll
      for (int kx = 0; kx < 4; kx++) {
        int ix = ix0 + kx;
        bool ok = (iy >= 0) && (iy < 96) && (ix >= 0) && (ix < 120);
        win[ic][ky * 4 + kx] = ok ? in[((n * 3 + ic) * 96 + iy) * 120 + ix] : 0.f;
      }
    }
  }
  #pragma unroll
  for (int oc = 0; oc < 16; oc++) {
    float acc = bias[oc];
    const float* wp = &wsm[oc * 48];
    #pragma unroll
    for (int ic = 0; ic < 3; ic++)
      #pragma unroll
      for (int k = 0; k < 16; k++)
        acc = fmaf(win[ic][k], wp[ic * 16 + k], acc);
    out[((nl * 16 + oc) * 48 + oy) * 60 + ox] = fmaxf(acc, 0.f);
  }
}

// ---------------- conv 16->16 (used for conv2 and conv3) --------------------
template <int IH, int IW, int OH, int OW>
__global__ __launch_bounds__(256) void conv16_kernel(
    const float* __restrict__ in, const float* __restrict__ w,
    const float* __restrict__ bias, float* __restrict__ out) {
  __shared__ float wsm[4096];  // 16*16*4*4
  int t = threadIdx.x;
  for (int i = t; i < 4096; i += 256) wsm[i] = w[i];
  __syncthreads();
  int idx = blockIdx.x * 256 + t;          // over CHUNK*OH*OW
  if (idx >= CHUNK * OH * OW) return;
  int ox = idx % OW;
  int oy = (idx / OW) % OH;
  int n  = idx / (OW * OH);
  int iy0 = oy * 2 - 1, ix0 = ox * 2 - 1;
  float acc[16];
  #pragma unroll
  for (int oc = 0; oc < 16; oc++) acc[oc] = bias[oc];
  for (int ic = 0; ic < 16; ic++) {
    float win[16];
    #pragma unroll
    for (int ky = 0; ky < 4; ky++) {
      int iy = iy0 + ky;
      #pragma unroll
      for (int kx = 0; kx < 4; kx++) {
        int ix = ix0 + kx;
        bool ok = (iy >= 0) && (iy < IH) && (ix >= 0) && (ix < IW);
        win[ky * 4 + kx] = ok ? in[((n * 16 + ic) * IH + iy) * IW + ix] : 0.f;
      }
    }
    #pragma unroll
    for (int oc = 0; oc < 16; oc++) {
      const float* wp = &wsm[(oc * 16 + ic) * 16];
      float a = acc[oc];
      #pragma unroll
      for (int k = 0; k < 16; k++) a = fmaf(win[k], wp[k], a);
      acc[oc] = a;
    }
  }
  #pragma unroll
  for (int oc = 0; oc < 16; oc++)
    out[((n * 16 + oc) * OH + oy) * OW + ox] = fmaxf(acc[oc], 0.f);
}

// ---------------- tiled fp32 GEMM, double-buffered, optional split-K --------
template <int EPI, bool ATOMIC>
__global__ __launch_bounds__(256) void gemm2_kernel(
    const float* __restrict__ A, const float* __restrict__ B,
    const float* __restrict__ bias, const float* __restrict__ res,
    float* __restrict__ C, int M, int N, int K, int klen) {
  __shared__ float As[2][16][68];
  __shared__ float Bs[2][16][64];
  int t = threadIdx.x;
  int m0 = blockIdx.y * 64, n0 = blockIdx.x * 64;
  int kb = blockIdx.z * klen;
  int arow = t >> 4, acol = t & 15;
  int brow = t >> 6, bcol = t & 63;
  int tx = t & 15, ty = t >> 4;
  float ra[4], rb[4];
  float acc[4][4] = {};

  #pragma unroll
  for (int i = 0; i < 4; i++) ra[i] = A[(m0 + arow + 16 * i) * K + kb + acol];
  #pragma unroll
  for (int i = 0; i < 4; i++) rb[i] = B[(kb + brow + 4 * i) * N + n0 + bcol];
  #pragma unroll
  for (int i = 0; i < 4; i++) As[0][acol][arow + 16 * i] = ra[i];
  #pragma unroll
  for (int i = 0; i < 4; i++) Bs[0][brow + 4 * i][bcol] = rb[i];
  __syncthreads();

  int nk = klen >> 4;
  for (int it = 0; it < nk; ++it) {
    int buf = it & 1;
    if (it + 1 < nk) {
      int k0 = kb + 16 * (it + 1);
      #pragma unroll
      for (int i = 0; i < 4; i++) ra[i] = A[(m0 + arow + 16 * i) * K + k0 + acol];
      #pragma unroll
      for (int i = 0; i < 4; i++) rb[i] = B[(k0 + brow + 4 * i) * N + n0 + bcol];
    }
    #pragma unroll
    for (int kk = 0; kk < 16; kk++) {
      float a[4], b[4];
      #pragma unroll
      for (int i = 0; i < 4; i++) a[i] = As[buf][kk][ty * 4 + i];
      #pragma unroll
      for (int j = 0; j < 4; j++) b[j] = Bs[buf][kk][tx * 4 + j];
      #pragma unroll
      for (int i = 0; i < 4; i++)
        #pragma unroll
        for (int j = 0; j < 4; j++)
          acc[i][j] = fmaf(a[i], b[j], acc[i][j]);
    }
    if (it + 1 < nk) {
      #pragma unroll
      for (int i = 0; i < 4; i++) As[buf ^ 1][acol][arow + 16 * i] = ra[i];
      #pragma unroll
      for (int i = 0; i < 4; i++) Bs[buf ^ 1][brow + 4 * i][bcol] = rb[i];
    }
    __syncthreads();
  }

  #pragma unroll
  for (int i = 0; i < 4; i++) {
    int m = m0 + ty * 4 + i;
    if (ATOMIC) {
      #pragma unroll
      for (int j = 0; j < 4; j++)
        atomicAdd(&C[m * N + n0 + tx * 4 + j], acc[i][j]);
    } else {
      #pragma unroll
      for (int j = 0; j < 4; j++) {
        int n = n0 + tx * 4 + j;
        float v = acc[i][j] + bias[n];
        if (EPI == 1) v = 0.5f * v * (1.f + erff(v * 0.70710678118654752f));
        else if (EPI == 2) v += res[m * N + n];
        C[m * N + n] = v;
      }
    }
  }
}

// ---------------- small init / bias kernels ---------------------------------
__global__ __launch_bounds__(256) void initc_pre_kernel(
    float* __restrict__ C, const float* __restrict__ bias,
    const float* __restrict__ pos) {
  int idx = blockIdx.x * 256 + threadIdx.x;   // 1024*256
  int n = idx & 255;
  int m = idx >> 8;
  C[idx] = bias[n] + pos[(m & (SEQ - 1)) * 256 + n];
}

__global__ __launch_bounds__(256) void initc_bias_kernel(
    float* __restrict__ C, const float* __restrict__ bias, int N) {
  int idx = blockIdx.x * 256 + threadIdx.x;
  C[idx] = bias[idx % N];
}

__global__ __launch_bounds__(256) void addbias_kernel(
    float* __restrict__ C, const float* __restrict__ bias) {
  int idx = blockIdx.x * 256 + threadIdx.x;   // N=256 only
  C[idx] += bias[idx & 255];
}

// ---------------- LayerNorm: one wave per row of 256 ------------------------
__global__ __launch_bounds__(256) void ln_kernel(
    const float* __restrict__ x, const float* __restrict__ g,
    const float* __restrict__ b, float* __restrict__ out) {
  int lane = threadIdx.x & 63;
  int wid  = threadIdx.x >> 6;
  int row  = blockIdx.x * 4 + wid;
  const float* xr = x + row * DMODEL;
  float v[4];
  #pragma unroll
  for (int i = 0; i < 4; i++) v[i] = xr[lane + 64 * i];
  float s = v[0] + v[1] + v[2] + v[3];
  #pragma unroll
  for (int o = 32; o >= 1; o >>= 1) s += __shfl_xor(s, o);
  float mu = s * (1.f / 256.f);
  float sq = 0.f;
  #pragma unroll
  for (int i = 0; i < 4; i++) { float d = v[i] - mu; sq = fmaf(d, d, sq); }
  #pragma unroll
  for (int o = 32; o >= 1; o >>= 1) sq += __shfl_xor(sq, o);
  float rs = rsqrtf(sq * (1.f / 256.f) + 1e-5f);
  float* orow = out + row * DMODEL;
  #pragma unroll
  for (int i = 0; i < 4; i++) {
    int c = lane + 64 * i;
    orow[c] = (v[i] - mu) * rs * g[c] + b[c];
  }
}

// ---------------- fused flash attention -------------------------------------
// Grid: 512 blocks = b(2) x h(8) x it(32); 256 threads = 16 rows x 16 lanes.
// Per block: rows i0..i0+15 of head (b,h). qkv layout [2,512,768] (q|k|v).
// x += softmax(causal(Q K^T / sqrt(32))) @ V
__global__ __launch_bounds__(256) void attn_fused_kernel(
    const float* __restrict__ qkv, float* __restrict__ x) {
  __shared__ float Qs[16][36];
  __shared__ float KVs[64][36];          // K tiles, then V tiles
  __shared__ float Osm[16][16][34];      // per-(row,lane-group) partials

  int t  = threadIdx.x;
  int it = blockIdx.x & 31;
  int h  = (blockIdx.x >> 5) & 7;
  int b  = blockIdx.x >> 8;
  int i0 = it * 16;
  int r  = t >> 4;          // 0..15 query row within tile
  int tx = t & 15;          // 0..15 lane within row group
  int i  = i0 + r;          // global query row
  int njt = (it >> 2) + 1;  // number of 64-wide causal j-tiles

  // stage Q tile [16][32]
  if (t < 128) {
    int qrow = t >> 3, qd4 = t & 7;
    *(float4*)&Qs[qrow][qd4 * 4] =
        *(const float4*)&qkv[(b * SEQ + i0 + qrow) * 768 + h * 32 + qd4 * 4];
  }
  __syncthreads();
  float4 qv[8];
  #pragma unroll
  for (int d4 = 0; d4 < 8; d4++) qv[d4] = *(float4*)&Qs[r][d4 * 4];

  float s[32];
  #pragma unroll
  for (int z = 0; z < 32; z++) s[z] = -1e30f;

  int kr = t >> 2, kd4 = t & 3;   // staging roles: 64 rows x 2 float4 each

  // ---- phase 1: scores ----
  #pragma unroll
  for (int jt = 0; jt < 8; jt++) {
    if (jt < njt) {
      int j0 = jt * 64;
      const float* kb = &qkv[(b * SEQ + j0 + kr) * 768 + DMODEL + h * 32];
      *(float4*)&KVs[kr][kd4 * 4]       = *(const float4*)&kb[kd4 * 4];
      *(float4*)&KVs[kr][(kd4 + 4) * 4] = *(const float4*)&kb[(kd4 + 4) * 4];
      __syncthreads();
      #pragma unroll
      for (int q = 0; q < 4; q++) {
        int jl = q * 16 + tx;
        int j  = j0 + jl;
        float acc = 0.f;
        #pragma unroll
        for (int d4 = 0; d4 < 8; d4++) {
          float4 kv = *(float4*)&KVs[jl][d4 * 4];
          acc = fmaf(qv[d4].x, kv.x, acc);
          acc = fmaf(qv[d4].y, kv.y, acc);
          acc = fmaf(qv[d4].z, kv.z, acc);
          acc = fmaf(qv[d4].w, kv.w, acc);
        }
        s[jt * 4 + q] = (j <= i) ? acc * 0.17677669529663687f : -1e30f;
      }
      __syncthreads();
    }
  }

  // ---- softmax over the row (16-lane group reduce) ----
  float mx = -1e30f;
  #pragma unroll
  for (int z = 0; z < 32; z++) mx = fmaxf(mx, s[z]);
  #pragma unroll
  for (int o = 8; o >= 1; o >>= 1) mx = fmaxf(mx, __shfl_xor(mx, o, 16));
  float sum = 0.f;
  #pragma unroll
  for (int z = 0; z < 32; z++) {
    float e = expf(s[z] - mx);
    s[z] = e;
    sum += e;
  }
  #pragma unroll
  for (int o = 8; o >= 1; o >>= 1) sum += __shfl_xor(sum, o, 16);
  float inv = 1.f / sum;
  #pragma unroll
  for (int z = 0; z < 32; z++) s[z] *= inv;

  // ---- phase 2: P @ V ----
  float o[32];
  #pragma unroll
  for (int z = 0; z < 32; z++) o[z] = 0.f;

  #pragma unroll
  for (int jt = 0; jt < 8; jt++) {
    if (jt < njt) {
      int j0 = jt * 64;
      const float* vb = &qkv[(b * SEQ + j0 + kr) * 768 + 2 * DMODEL + h * 32];
      *(float4*)&KVs[kr][kd4 * 4]       = *(const float4*)&vb[kd4 * 4];
      *(float4*)&KVs[kr][(kd4 + 4) * 4] = *(const float4*)&vb[(kd4 + 4) * 4];
      __syncthreads();
      #pragma unroll
      for (int q = 0; q < 4; q++) {
        int jl = q * 16 + tx;
        float p = s[jt * 4 + q];
        #pragma unroll
        for (int d4 = 0; d4 < 8; d4++) {
          float4 vv = *(float4*)&KVs[jl][d4 * 4];
          o[d4 * 4 + 0] = fmaf(p, vv.x, o[d4 * 4 + 0]);
          o[d4 * 4 + 1] = fmaf(p, vv.y, o[d4 * 4 + 1]);
          o[d4 * 4 + 2] = fmaf(p, vv.z, o[d4 * 4 + 2]);
          o[d4 * 4 + 3] = fmaf(p, vv.w, o[d4 * 4 + 3]);
        }
      }
      __syncthreads();
    }
  }

  // ---- reduce o across the 16-lane row group via LDS ----
  #pragma unroll
  for (int d2 = 0; d2 < 16; d2++)
    *(float2*)&Osm[r][tx][d2 * 2] = make_float2(o[d2 * 2], o[d2 * 2 + 1]);
  __syncthreads();
  float2 acc2 = make_float2(0.f, 0.f);
  #pragma unroll
  for (int tx2 = 0; tx2 < 16; tx2++) {
    float2 v = *(float2*)&Osm[r][tx2][tx * 2];
    acc2.x += v.x;
    acc2.y += v.y;
  }
  int base = (b * SEQ + i) * DMODEL + h * 32 + tx * 2;
  float2 old = *(float2*)&x[base];
  old.x += acc2.x;
  old.y += acc2.y;
  *(float2*)&x[base] = old;
}

// ---------------- global standardization ------------------------------------
__global__ __launch_bounds__(256) void reduce1_kernel(
    const float* __restrict__ enc, double* __restrict__ part) {
  int t = threadIdx.x;
  double s = 0.0, q = 0.0;
  for (int i = blockIdx.x * 256 + t; i < 262144; i += 256 * 256) {
    double v = (double)enc[i];
    s += v; q += v * v;
  }
  #pragma unroll
  for (int o = 32; o >= 1; o >>= 1) { s += __shfl_xor(s, o); q += __shfl_xor(q, o); }
  __shared__ double ls[4], lq[4];
  int lane = t & 63, wid = t >> 6;
  if (lane == 0) { ls[wid] = s; lq[wid] = q; }
  __syncthreads();
  if (t == 0) {
    part[blockIdx.x * 2]     = ls[0] + ls[1] + ls[2] + ls[3];
    part[blockIdx.x * 2 + 1] = lq[0] + lq[1] + lq[2] + lq[3];
  }
}

__global__ __launch_bounds__(256) void reduce2_kernel(
    const double* __restrict__ part, float* __restrict__ stats) {
  int t = threadIdx.x;
  double s = part[t * 2], q = part[t * 2 + 1];
  #pragma unroll
  for (int o = 32; o >= 1; o >>= 1) { s += __shfl_xor(s, o); q += __shfl_xor(q, o); }
  __shared__ double ls[4], lq[4];
  int lane = t & 63, wid = t >> 6;
  if (lane == 0) { ls[wid] = s; lq[wid] = q; }
  __syncthreads();
  if (t == 0) {
    double S = ls[0] + ls[1] + ls[2] + ls[3];
    double Q = lq[0] + lq[1] + lq[2] + lq[3];
    double n = 262144.0;
    double mean = S / n;
    double var  = (Q - n * mean * mean) / (n - 1.0);
    stats[0] = (float)mean;
    stats[1] = (float)(1.0 / sqrt(var));
  }
}

__global__ __launch_bounds__(256) void norm_kernel(
    const float* __restrict__ enc, const float* __restrict__ stats,
    float* __restrict__ out) {
  int i = blockIdx.x * 256 + threadIdx.x;
  float mean = stats[0], inv = stats[1];
  out[i] = (enc[i] - mean) * inv + 1e-10f;
}

// ---------------------------------------------------------------------------
extern "C" void kernel_launch(void* const* d_in, const int* in_sizes, int n_in,
                              void* d_out, int out_size, void* d_ws, size_t ws_size,
                              hipStream_t stream) {
  const float* state   = (const float*)d_in[0];
  const float* conv_w1 = (const float*)d_in[1];
  const float* conv_b1 = (const float*)d_in[2];
  const float* conv_w2 = (const float*)d_in[3];
  const float* conv_b2 = (const float*)d_in[4];
  const float* conv_w3 = (const float*)d_in[5];
  const float* conv_b3 = (const float*)d_in[6];
  const float* pre_w   = (const float*)d_in[7];
  const float* pre_b   = (const float*)d_in[8];
  const float* pos_w   = (const float*)d_in[9];
  const float* ln1_g   = (const float*)d_in[10];
  const float* ln1_b   = (const float*)d_in[11];
  const float* enc_w   = (const float*)d_in[12];
  const float* enc_bi  = (const float*)d_in[13];
  const float* ln2_g   = (const float*)d_in[14];
  const float* ln2_b   = (const float*)d_in[15];
  const float* ffn_w1  = (const float*)d_in[16];
  const float* ffn_b1  = (const float*)d_in[17];
  const float* ffn_w2  = (const float*)d_in[18];
  const float* ffn_b2  = (const float*)d_in[19];
  const float* emb_w   = (const float*)d_in[20];
  const float* emb_b   = (const float*)d_in[21];
  float* out = (float*)d_out;
  char* ws = (char*)d_ws;

  const size_t OFF_C1C = 0;                         // 47185920
  const size_t OFF_C2C = OFF_C1C + 47185920;        // 11796480
  const size_t OFF_C3  = OFF_C2C + 11796480;        // 11796480
  const size_t OFF_X   = OFF_C3  + 11796480;        // 1048576
  const size_t OFF_XN  = OFF_X   + 1048576;         // 1048576
  const size_t OFF_QKV = OFF_XN  + 1048576;         // 3145728
  const size_t OFF_H1  = OFF_QKV + 3145728;         // 4194304
  const size_t OFF_ENC = OFF_H1  + 4194304;         // 1048576
  const size_t OFF_RED = OFF_ENC + 1048576;

  float*  c1c  = (float*)(ws + OFF_C1C);
  float*  c2c  = (float*)(ws + OFF_C2C);
  float*  c3   = (float*)(ws + OFF_C3);
  float*  x    = (float*)(ws + OFF_X);
  float*  xn   = (float*)(ws + OFF_XN);
  float*  qkv  = (float*)(ws + OFF_QKV);
  float*  h1   = (float*)(ws + OFF_H1);
  float*  encb = (float*)(ws + OFF_ENC);
  double* part = (double*)(ws + OFF_RED);
  float*  stats= (float*)(ws + OFF_RED + 4096);

  for (int chunk = 0; chunk < NCHUNK; chunk++) {
    conv1_kernel<<<2880, 256, 0, stream>>>(state, conv_w1, conv_b1, c1c, chunk * CHUNK);
    conv16_kernel<48, 60, 24, 30><<<720, 256, 0, stream>>>(c1c, conv_w2, conv_b2, c2c);
    conv16_kernel<24, 30, 12, 15><<<180, 256, 0, stream>>>(
        c2c, conv_w3, conv_b3, c3 + (size_t)chunk * CHUNK * 2880);
  }

  // pre projection: x = bias + pos, then split-K atomic accumulate (S=12)
  initc_pre_kernel<<<1024, 256, 0, stream>>>(x, pre_b, pos_w);
  gemm2_kernel<0, true><<<dim3(4, 16, 12), 256, 0, stream>>>(
      c3, pre_w, nullptr, nullptr, x, 1024, 256, 2880, 240);

  for (int k = 0; k < 4; k++) {
    ln_kernel<<<256, 256, 0, stream>>>(x, ln1_g + k * 256, ln1_b + k * 256, xn);
    initc_bias_kernel<<<3072, 256, 0, stream>>>(qkv, enc_bi + k * 768, 768);
    gemm2_kernel<0, true><<<dim3(12, 16, 2), 256, 0, stream>>>(
        xn, enc_w + (size_t)k * 256 * 768, nullptr, nullptr, qkv,
        1024, 768, 256, 128);
    attn_fused_kernel<<<512, 256, 0, stream>>>(qkv, x);
    ln_kernel<<<256, 256, 0, stream>>>(x, ln2_g + k * 256, ln2_b + k * 256, x);
    gemm2_kernel<1, false><<<dim3(16, 16, 1), 256, 0, stream>>>(
        x, ffn_w1 + (size_t)k * 256 * 1024, ffn_b1 + k * 1024, nullptr, h1,
        1024, 1024, 256, 256);
    addbias_kernel<<<1024, 256, 0, stream>>>(x, ffn_b2 + k * 256);
    gemm2_kernel<0, true><<<dim3(4, 16, 8), 256, 0, stream>>>(
        h1, ffn_w2 + (size_t)k * 1024 * 256, nullptr, nullptr, x,
        1024, 256, 1024, 128);
  }

  initc_bias_kernel<<<1024, 256, 0, stream>>>(encb, emb_b, 256);
  gemm2_kernel<0, true><<<dim3(4, 16, 4), 256, 0, stream>>>(
      x, emb_w, nullptr, nullptr, encb, 1024, 256, 256, 64);

  reduce1_kernel<<<256, 256, 0, stream>>>(encb, part);
  reduce2_kernel<<<1, 256, 0, stream>>>(part, stats);
  norm_kernel<<<1024, 256, 0, stream>>>(encb, stats, out);
}